// Round 1
// baseline (302.501 us; speedup 1.0000x reference)
//
#include <hip/hip_runtime.h>
#include <math.h>

// Problem constants (match reference: N=8192, D=200, k=100)
#define NN 8192
#define DD 200
#define KK 100

// Histogram config: range [-8, 8) over s = b_i + e_j (actual |s| < ~2.3)
#define NBINS 1024
#define NHBLK 256          // histogram blocks (each writes a private hist)
#define HSCALE 64.0f       // NBINS / 16
#define BINW 0.015625f     // 16 / NBINS
#define CAND_CAP 16384

// ws layout in 4-byte units (total ~1.2 MB)
#define OFF_B 0                          // float b[8192]
#define OFF_E 8192                       // float e[8192]
#define OFF_SUMS 16384                   // float S_b, S_e
#define OFF_T 16386                      // float collect threshold
#define OFF_CC 16387                     // u32 candidate count
#define OFF_BH 16400                     // u32 blockhist[256][1024]
#define OFF_CV (OFF_BH + NHBLK * NBINS)  // float cand_val[CAND_CAP]
#define OFF_CI (OFF_CV + CAND_CAP)       // u32  cand_idx[CAND_CAP]

// K1: b[i] = G[i,:]·wb, e[i] = G[i,:]·we. One wave64 per row, coalesced row read.
__global__ __launch_bounds__(256) void k_be(const float* __restrict__ G,
                                            const float* __restrict__ wb,
                                            const float* __restrict__ we,
                                            float* __restrict__ wsf) {
    int gid = blockIdx.x * 256 + threadIdx.x;
    int row = gid >> 6;
    int lane = gid & 63;
    if (row >= NN) return;
    const float* r = G + (size_t)row * DD;
    float pb = 0.f, pe = 0.f;
    for (int d = lane; d < DD; d += 64) {
        float g = r[d];
        pb = fmaf(g, wb[d], pb);
        pe = fmaf(g, we[d], pe);
    }
    for (int off = 32; off; off >>= 1) {
        pb += __shfl_xor(pb, off, 64);
        pe += __shfl_xor(pe, off, 64);
    }
    if (lane == 0) { wsf[OFF_B + row] = pb; wsf[OFF_E + row] = pe; }
}

// K2: S_b = sum exp(b), S_e = sum exp(e). Single block, no atomics needed.
__global__ __launch_bounds__(1024) void k_sums(float* __restrict__ wsf) {
    __shared__ float sb[1024], se[1024];
    int tid = threadIdx.x;
    float ab = 0.f, ae = 0.f;
    for (int i = tid; i < NN; i += 1024) {
        ab += expf(wsf[OFF_B + i]);
        ae += expf(wsf[OFF_E + i]);
    }
    sb[tid] = ab; se[tid] = ae;
    __syncthreads();
    for (int off = 512; off; off >>= 1) {
        if (tid < off) { sb[tid] += sb[tid + off]; se[tid] += se[tid + off]; }
        __syncthreads();
    }
    if (tid == 0) { wsf[OFF_SUMS] = sb[0]; wsf[OFF_SUMS + 1] = se[0]; }
}

// K3: histogram of s = b_i + e_j over upper triangle (j >= i) into per-block
// private global hists (LDS atomics only; plain stores to global).
__global__ __launch_bounds__(512) void k_hist(const float* __restrict__ wsf,
                                              unsigned* __restrict__ wsu) {
    __shared__ unsigned h[NBINS];
    int tid = threadIdx.x;
    for (int i = tid; i < NBINS; i += 512) h[i] = 0;
    __syncthreads();
    const float* b = wsf + OFF_B;
    const float* e = wsf + OFF_E;
    for (int r = blockIdx.x; r < NN; r += NHBLK) {
        float bi = b[r];
        for (int j = r + tid; j < NN; j += 512) {
            float s = bi + e[j];
            int bin = (int)fmaf(s, HSCALE, 512.0f);   // (s + 8) * 64
            bin = bin < 0 ? 0 : (bin > NBINS - 1 ? NBINS - 1 : bin);
            atomicAdd(&h[bin], 1u);
        }
    }
    __syncthreads();
    unsigned* out = wsu + OFF_BH + blockIdx.x * NBINS;
    for (int i = tid; i < NBINS; i += 512) out[i] = h[i];
}

// K4: reduce 256 private hists, suffix-scan from the top for the bin holding
// rank KK; threshold = lower edge of (that bin - 1) for float-edge safety.
// Also zeroes the candidate counter (ws is poisoned before every launch).
__global__ __launch_bounds__(1024) void k_thresh(unsigned* __restrict__ wsu,
                                                 float* __restrict__ wsf) {
    __shared__ unsigned fh[NBINS];
    int tid = threadIdx.x;  // == bin index (NBINS = 1024)
    unsigned s = 0;
    const unsigned* bh = wsu + OFF_BH;
    for (int blk = 0; blk < NHBLK; ++blk) s += bh[blk * NBINS + tid];
    fh[tid] = s;
    __syncthreads();
    if (tid == 0) {
        unsigned cum = 0;
        int bstar = 0;
        for (int bin = NBINS - 1; bin >= 0; --bin) {
            cum += fh[bin];
            if (cum >= KK) { bstar = bin; break; }
        }
        int tb = bstar - 1; if (tb < 0) tb = 0;
        wsf[OFF_T] = -8.0f + (float)tb * BINW;
        wsu[OFF_CC] = 0;
    }
}

// K5: collect all upper-triangle pairs with s >= t (expected ~140).
__global__ __launch_bounds__(512) void k_collect(const float* __restrict__ wsf,
                                                 unsigned* __restrict__ wsu) {
    const float* b = wsf + OFF_B;
    const float* e = wsf + OFF_E;
    float t = wsf[OFF_T];
    float* cv = (float*)wsu + OFF_CV;
    unsigned* ci = wsu + OFF_CI;
    unsigned* cc = wsu + OFF_CC;
    for (int r = blockIdx.x; r < NN; r += 256) {
        float bi = b[r];
        for (int j = r + (int)threadIdx.x; j < NN; j += 512) {
            float s = bi + e[j];
            if (s >= t) {
                unsigned pos = atomicAdd(cc, 1u);
                if (pos < CAND_CAP) {
                    cv[pos] = s;
                    ci[pos] = ((unsigned)r << 13) | (unsigned)j;
                }
            }
        }
    }
}

// K6: single-block iterative top-100 with jax tie-break (value desc, flat idx asc).
// Writes indices as float32 (harness concatenates int32+float32 outputs -> float).
__global__ __launch_bounds__(256) void k_select(unsigned* __restrict__ wsu,
                                                float* __restrict__ out) {
    float* wsf = (float*)wsu;
    __shared__ float sv[256];
    __shared__ unsigned si[256];
    __shared__ int ss[256];
    int tid = threadIdx.x;
    unsigned M = wsu[OFF_CC];
    if (M > CAND_CAP) M = CAND_CAP;
    float inv_den = 1.0f / (wsf[OFF_SUMS] * wsf[OFF_SUMS + 1]);
    float* cv = wsf + OFF_CV;
    unsigned* ci = wsu + OFF_CI;
    for (int k = 0; k < KK; ++k) {
        float bv = -INFINITY;
        unsigned bidx = 0xFFFFFFFFu;
        int bslot = -1;
        for (unsigned c = tid; c < M; c += 256) {
            float v = cv[c];
            unsigned fi = ci[c];
            if (v > bv || (v == bv && fi < bidx)) { bv = v; bidx = fi; bslot = (int)c; }
        }
        sv[tid] = bv; si[tid] = bidx; ss[tid] = bslot;
        __syncthreads();
        for (int off = 128; off; off >>= 1) {
            if (tid < off) {
                float v2 = sv[tid + off];
                unsigned i2 = si[tid + off];
                if (v2 > sv[tid] || (v2 == sv[tid] && i2 < si[tid])) {
                    sv[tid] = v2; si[tid] = i2; ss[tid] = ss[tid + off];
                }
            }
            __syncthreads();
        }
        if (tid == 0) {
            unsigned fi = si[0];
            out[2 * k]     = (float)(fi >> 13);     // row = flat / 8192
            out[2 * k + 1] = (float)(fi & 8191u);   // col = flat % 8192
            out[200 + k]   = expf(sv[0]) * inv_den;
            if (ss[0] >= 0) cv[ss[0]] = -INFINITY;  // remove winner
        }
        __syncthreads();
    }
}

extern "C" void kernel_launch(void* const* d_in, const int* in_sizes, int n_in,
                              void* d_out, int out_size, void* d_ws, size_t ws_size,
                              hipStream_t stream) {
    const float* G  = (const float*)d_in[0];
    const float* wb = (const float*)d_in[1];
    const float* we = (const float*)d_in[2];
    // d_in[3] is k (=100), baked into KK.
    float* out = (float*)d_out;
    float* wsf = (float*)d_ws;
    unsigned* wsu = (unsigned*)d_ws;

    hipLaunchKernelGGL(k_be, dim3(2048), dim3(256), 0, stream, G, wb, we, wsf);
    hipLaunchKernelGGL(k_sums, dim3(1), dim3(1024), 0, stream, wsf);
    hipLaunchKernelGGL(k_hist, dim3(NHBLK), dim3(512), 0, stream, wsf, wsu);
    hipLaunchKernelGGL(k_thresh, dim3(1), dim3(1024), 0, stream, wsu, wsf);
    hipLaunchKernelGGL(k_collect, dim3(256), dim3(512), 0, stream, wsf, wsu);
    hipLaunchKernelGGL(k_select, dim3(1), dim3(256), 0, stream, wsu, out);
}

// Round 2
// 100.436 us; speedup vs baseline: 3.0119x; 3.0119x over previous
//
#include <hip/hip_runtime.h>
#include <math.h>

// Problem constants (reference: N=8192, D=200, k=100)
#define NN 8192
#define DD 200
#define KK 100

// s = b_i + e_j histogram grid: 1024 bins over [-8, 8), width 2^-6 (exact fp)
#define NBINS 1024
#define HSCALE 64.0f
#define BINW 0.015625f
#define CAND_CAP 4096

// ws layout (4-byte units), ~107 KB total
#define OFF_B 0                  // float b[8192]
#define OFF_E 8192               // float e[8192]
#define OFF_SUMS 16384           // float S_b, S_e
#define OFF_EMAX 16386           // float max(e)
#define OFF_TMAX 16387           // u32 best threshold bin (atomicMax)
#define OFF_CC 16388             // u32 candidate count
#define OFF_HB 16400             // u32 hist_b[1024]
#define OFF_HE 17424             // u32 hist_e[1024]
#define OFF_CV 18448             // float cand_val[CAND_CAP]
#define OFF_CI (OFF_CV + CAND_CAP) // u32 cand_idx[CAND_CAP]

// K1: b[i] = G[i,:]·wb, e[i] = G[i,:]·we. One wave per row; 50 lanes × float4 = 200.
__global__ __launch_bounds__(256) void k_be(const float* __restrict__ G,
                                            const float* __restrict__ wb,
                                            const float* __restrict__ we,
                                            float* __restrict__ wsf) {
    int gid = blockIdx.x * 256 + threadIdx.x;
    int row = gid >> 6;
    int lane = gid & 63;
    float pb = 0.f, pe = 0.f;
    if (lane < 50) {
        float4 g = ((const float4*)(G + (size_t)row * DD))[lane];
        float4 B = ((const float4*)wb)[lane];
        float4 E = ((const float4*)we)[lane];
        pb = fmaf(g.x, B.x, fmaf(g.y, B.y, fmaf(g.z, B.z, g.w * B.w)));
        pe = fmaf(g.x, E.x, fmaf(g.y, E.y, fmaf(g.z, E.z, g.w * E.w)));
    }
    for (int off = 32; off; off >>= 1) {
        pb += __shfl_xor(pb, off, 64);
        pe += __shfl_xor(pe, off, 64);
    }
    if (lane == 0) { wsf[OFF_B + row] = pb; wsf[OFF_E + row] = pe; }
}

// K2: single block — exp-sums, e_max, marginal histograms of b and e.
// Also initializes TMAX and CC (ws is re-poisoned before every launch).
__global__ __launch_bounds__(1024) void k_stats(float* __restrict__ wsf,
                                                unsigned* __restrict__ wsu) {
    __shared__ unsigned hb[NBINS], he[NBINS];
    __shared__ float red[1024];
    int tid = threadIdx.x;
    hb[tid] = 0; he[tid] = 0;
    __syncthreads();
    float ab = 0.f, ae = 0.f, em = -1e30f;
    for (int i = tid; i < NN; i += 1024) {
        float bv = wsf[OFF_B + i], ev = wsf[OFF_E + i];
        ab += expf(bv); ae += expf(ev);
        em = fmaxf(em, ev);
        int p = (int)fmaf(bv, HSCALE, 512.f); p = min(max(p, 0), NBINS - 1);
        int q = (int)fmaf(ev, HSCALE, 512.f); q = min(max(q, 0), NBINS - 1);
        atomicAdd(&hb[p], 1u);
        atomicAdd(&he[q], 1u);
    }
    red[tid] = ab; __syncthreads();
    for (int off = 512; off; off >>= 1) { if (tid < off) red[tid] += red[tid + off]; __syncthreads(); }
    if (tid == 0) wsf[OFF_SUMS] = red[0];
    __syncthreads();
    red[tid] = ae; __syncthreads();
    for (int off = 512; off; off >>= 1) { if (tid < off) red[tid] += red[tid + off]; __syncthreads(); }
    if (tid == 0) wsf[OFF_SUMS + 1] = red[0];
    __syncthreads();
    red[tid] = em; __syncthreads();
    for (int off = 512; off; off >>= 1) { if (tid < off) red[tid] = fmaxf(red[tid], red[tid + off]); __syncthreads(); }
    if (tid == 0) { wsf[OFF_EMAX] = red[0]; wsu[OFF_TMAX] = 0u; wsu[OFF_CC] = 0u; }
    __syncthreads();
    wsu[OFF_HB + tid] = hb[tid];
    wsu[OFF_HE + tid] = he[tid];
}

// K3: threshold via marginal-histogram correlation. Bin lower edges:
// blo_p + elo_q >= T_t  <=>  p + q >= t + 512 (exact integer form), so
// cnt(t) = sum_p hb[p] * suffix_e[t+512-p] is a LOWER bound on the true
// full-matrix count of s >= T_t. cnt >= 200 => upper-tri count >= 100.
// 64 blocks x 16 waves; each wave owns one threshold bin t.
__global__ __launch_bounds__(1024) void k_thresh(unsigned* __restrict__ wsu) {
    __shared__ unsigned sfx[NBINS];
    __shared__ unsigned hbs[NBINS];
    int tid = threadIdx.x;
    sfx[tid] = wsu[OFF_HE + tid];
    hbs[tid] = wsu[OFF_HB + tid];
    __syncthreads();
    for (int d = 1; d < NBINS; d <<= 1) {           // suffix sum (Hillis-Steele)
        unsigned v = (tid + d < NBINS) ? sfx[tid + d] : 0u;
        __syncthreads();
        sfx[tid] += v;
        __syncthreads();
    }
    int lane = tid & 63;
    int t = blockIdx.x * 16 + (tid >> 6);
    unsigned cnt = 0;
    for (int k = 0; k < 16; ++k) {
        int p = lane + (k << 6);
        int idx = t + 512 - p;
        unsigned s = (idx <= 0) ? sfx[0] : ((idx > NBINS - 1) ? 0u : sfx[idx]);
        cnt += hbs[p] * s;
    }
    for (int off = 32; off; off >>= 1) cnt += __shfl_xor(cnt, off, 64);
    if (lane == 0 && cnt >= 2 * KK) atomicMax(wsu + OFF_TMAX, (unsigned)t);
}

// K4: collect upper-triangle pairs with s >= t (one-bin safety margin).
// Row early-out: row can only qualify if b_i + e_max >= t (~30 of 8192 rows).
__global__ __launch_bounds__(256) void k_collect(float* __restrict__ wsf,
                                                 unsigned* __restrict__ wsu) {
    const float* b = wsf + OFF_B;
    const float* e = wsf + OFF_E;
    int tmax = (int)wsu[OFF_TMAX];
    float t = -8.0f + (float)(tmax - 1) * BINW;
    float emax = wsf[OFF_EMAX];
    for (int r = blockIdx.x; r < NN; r += 256) {
        float bi = b[r];
        if (bi + emax < t) continue;
        for (int j = r + (int)threadIdx.x; j < NN; j += 256) {
            float s = bi + e[j];
            if (s >= t) {
                unsigned pos = atomicAdd(wsu + OFF_CC, 1u);
                if (pos < CAND_CAP) {
                    wsf[OFF_CV + pos] = s;
                    wsu[OFF_CI + pos] = ((unsigned)r << 13) | (unsigned)j;
                }
            }
        }
    }
}

// K5: rank-based top-100, single pass. rank(c) = #{better}; better =
// (v>, or v== and idx<) — exactly jax top_k order. rank<100 writes directly.
__global__ __launch_bounds__(1024) void k_select(unsigned* __restrict__ wsu,
                                                 float* __restrict__ out) {
    float* wsf = (float*)wsu;
    __shared__ float cv[CAND_CAP];
    __shared__ unsigned ci[CAND_CAP];
    int tid = threadIdx.x;
    unsigned M = wsu[OFF_CC];
    if (M > CAND_CAP) M = CAND_CAP;
    for (unsigned c = tid; c < M; c += 1024) {
        cv[c] = wsf[OFF_CV + c];
        ci[c] = wsu[OFF_CI + c];
    }
    __syncthreads();
    float inv_den = 1.0f / (wsf[OFF_SUMS] * wsf[OFF_SUMS + 1]);
    for (unsigned c = tid; c < M; c += 1024) {
        float v = cv[c];
        unsigned fi = ci[c];
        int rank = 0;
        for (unsigned m = 0; m < M; ++m) {
            float vm = cv[m];
            rank += (vm > v) || (vm == v && ci[m] < fi);
        }
        if (rank < KK) {
            out[2 * rank]     = (float)(fi >> 13);
            out[2 * rank + 1] = (float)(fi & 8191u);
            out[200 + rank]   = expf(v) * inv_den;
        }
    }
}

extern "C" void kernel_launch(void* const* d_in, const int* in_sizes, int n_in,
                              void* d_out, int out_size, void* d_ws, size_t ws_size,
                              hipStream_t stream) {
    const float* G  = (const float*)d_in[0];
    const float* wb = (const float*)d_in[1];
    const float* we = (const float*)d_in[2];
    float* out = (float*)d_out;
    float* wsf = (float*)d_ws;
    unsigned* wsu = (unsigned*)d_ws;

    hipLaunchKernelGGL(k_be, dim3(2048), dim3(256), 0, stream, G, wb, we, wsf);
    hipLaunchKernelGGL(k_stats, dim3(1), dim3(1024), 0, stream, wsf, wsu);
    hipLaunchKernelGGL(k_thresh, dim3(64), dim3(1024), 0, stream, wsu);
    hipLaunchKernelGGL(k_collect, dim3(256), dim3(256), 0, stream, wsf, wsu);
    hipLaunchKernelGGL(k_select, dim3(1), dim3(1024), 0, stream, wsu, out);
}